// Round 17
// baseline (234.922 us; speedup 1.0000x reference)
//
#include <hip/hip_runtime.h>
#include <hip/hip_bf16.h>

typedef __attribute__((ext_vector_type(4))) float f32x4;
typedef __attribute__((ext_vector_type(8))) short bf16x8;
typedef __attribute__((ext_vector_type(4))) short short4v;

__device__ __forceinline__ short f2bf(float f) {
  union { float f; unsigned u; } x; x.f = f;
  unsigned r = x.u + 0x7fffu + ((x.u >> 16) & 1u);
  return (short)(r >> 16);
}

__device__ __forceinline__ float fexp2(float x) {
#if __has_builtin(__builtin_amdgcn_exp2f)
  return __builtin_amdgcn_exp2f(x);
#else
  return exp2f(x);
#endif
}

#define WAITVM(n) { asm volatile("s_waitcnt vmcnt(" #n ")" ::: "memory"); __builtin_amdgcn_sched_barrier(0); }
#define BARRIER() { __builtin_amdgcn_sched_barrier(0); asm volatile("s_barrier" ::: "memory"); __builtin_amdgcn_sched_barrier(0); }
#define GLD16(g, l) __builtin_amdgcn_global_load_lds((const __attribute__((address_space(1))) void*)(g), (__attribute__((address_space(3))) void*)(l), 16, 0, 0)

// Q pre-scale folded into the QKV GEMM epilogue: 1/sqrt(dh) * log2(e)
#define QSC (0.08838834764831845f * 1.4426950408889634f)

// ---------------- fused cast f32 -> bf16 (RNE), 8 elems/thread, 6 slices ----------------
__global__ __launch_bounds__(256) void cast6_kernel(const float* __restrict__ x,
                                                    const float* __restrict__ w0,
                                                    const float* __restrict__ w1,
                                                    const float* __restrict__ w2,
                                                    const float* __restrict__ w3,
                                                    short* __restrict__ xb,
                                                    short* __restrict__ qkv,
                                                    short* __restrict__ wo) {
  const int y = blockIdx.y;
  const float* in;
  short* out;
  if (y < 3)      { in = (y == 0) ? w0 : (y == 1) ? w1 : w2; out = qkv + (long)y * 4194304; }
  else if (y == 3){ in = w3; out = wo; }
  else            { in = x + (long)(y - 4) * 4194304; out = xb + (long)(y - 4) * 4194304; }
  const int i = blockIdx.x * 256 + threadIdx.x;
  const float4 a = reinterpret_cast<const float4*>(in)[2 * i];
  const float4 b = reinterpret_cast<const float4*>(in)[2 * i + 1];
  bf16x8 s;
  s[0] = f2bf(a.x); s[1] = f2bf(a.y); s[2] = f2bf(a.z); s[3] = f2bf(a.w);
  s[4] = f2bf(b.x); s[5] = f2bf(b.y); s[6] = f2bf(b.z); s[7] = f2bf(b.w);
  reinterpret_cast<bf16x8*>(out)[i] = s;
}

// ---------------- fused QKV GEMM: 128x384 tile, BK=64, 1-vmcnt/2-barrier per kt ----------------
// Round-17 sync proof (FIFO, per-wave counts): stages per kt, in order:
// P0 issues {A'',H0''}(4), P1 issues {H1''}(2), P2 issues {H2''}(2) -> 8/kt, all into nxt.
// At kt's WAITVM(4) (after issuing A'',H0''): outstanding = kt-1's {H1',H2'}(4) + {A'',H0''}(4);
// keeping the 4 newest retires H1',H2' AND everything older (A',H0') => ALL of cur retired.
// BARRIER(pub) then publishes cur to every wave => P0/P1/P2 reads of cur are race-free with
// no further waits. BARRIER(end) after P2's MFMA = WAR fence: all reads of cur done before
// kt+1 stages into it. Prologue: 8 GLD into buf0; kt=0's WAITVM(4) retires them (12 out, keep 4).
__global__ __launch_bounds__(512, 2) void gemm_qkv8(const short* __restrict__ A,
                                                    const short* __restrict__ W,
                                                    short* __restrict__ Qo,
                                                    short* __restrict__ Ko,
                                                    short* __restrict__ Vt) {
  __shared__ __align__(1024) char lds[131072];   // 2 buf x 64KB
  const int tid  = threadIdx.x;
  const int lane = tid & 63;
  const int w    = tid >> 6;
  const int wm   = w >> 2, wn = w & 3;
  const int l16  = lane & 15, g = lane >> 4;
  const int K    = 2048;

  int id = (int)blockIdx.x;
  id = (id & 7) * 64 + (id >> 3);
  const int mb = id & 31, nb = id >> 5;
  const long m0 = (long)mb * 128, n0 = (long)nb * 384;

  const int srow = lane >> 3;
  const int scol = ((lane & 7) ^ srow) * 8;
  const int csw  = (l16 & 7) << 4;

  f32x4 acc[4][6];
  #pragma unroll
  for (int a = 0; a < 4; a++)
    #pragma unroll
    for (int b = 0; b < 6; b++) acc[a][b] = (f32x4){0.f, 0.f, 0.f, 0.f};

  #define STAGE_A(kt, buf)                                                          \
    {                                                                               \
      const short* s0_ = A + (m0 + w * 16 + srow) * K + (kt) * 64 + scol;           \
      char* d_ = lds + (buf) * 65536 + (w * 16) * 128;                              \
      GLD16(s0_, d_);                                                               \
      GLD16(s0_ + 8LL * K, d_ + 1024);                                              \
    }
  #define STAGE_B(h, kt, buf)                                                       \
    {                                                                               \
      const short* s0_ = W + (n0 + (h) * 128 + w * 16 + srow) * K + (kt) * 64 + scol; \
      char* d_ = lds + (buf) * 65536 + 16384 + (h) * 16384 + (w * 16) * 128;        \
      GLD16(s0_, d_);                                                               \
      GLD16(s0_ + 8LL * K, d_ + 1024);                                              \
    }

  #define RDA(buf, fmL, k) (*reinterpret_cast<const bf16x8*>(                       \
      lds + (buf) * 65536 + ((wm * 64 + (fmL) * 16 + l16) * 128) +                  \
      ((((k) * 64 + g * 16)) ^ csw)))
  #define RDB(buf, h, j, k) (*reinterpret_cast<const bf16x8*>(                      \
      lds + (buf) * 65536 + 16384 + (h) * 16384 +                                   \
      ((wn * 16 + (j) * 64 + l16) * 128) + ((((k) * 64 + g * 16)) ^ csw)))

  // prologue: stage full kt=0 tile into buf0 (no wait needed here)
  STAGE_A(0, 0);
  STAGE_B(0, 0, 0);
  STAGE_B(1, 0, 0);
  STAGE_B(2, 0, 0);

  bf16x8 af[4][2], bfr[2][2];
  for (int kt = 0; kt < 32; ++kt) {
    const int cur = kt & 1, nxt = cur ^ 1;
    const int ks = (kt + 1 < 32) ? (kt + 1) : kt;

    // issue next-tile A,H0; single wait retires ALL of cur; publish
    STAGE_A(ks, nxt);
    STAGE_B(0, ks, nxt);
    WAITVM(4);
    BARRIER();   // B_pub: cur fully valid for all waves

    // ---- P0: A x H0 ----
    #pragma unroll
    for (int fm = 0; fm < 4; fm++)
      #pragma unroll
      for (int k = 0; k < 2; k++) af[fm][k] = RDA(cur, fm, k);
    #pragma unroll
    for (int j = 0; j < 2; j++)
      #pragma unroll
      for (int k = 0; k < 2; k++) bfr[j][k] = RDB(cur, 0, j, k);
    STAGE_B(1, ks, nxt);
    __builtin_amdgcn_s_setprio(1);
    #pragma unroll
    for (int fm = 0; fm < 4; fm++)
      #pragma unroll
      for (int j = 0; j < 2; j++)
        #pragma unroll
        for (int k = 0; k < 2; k++)
          acc[fm][j] = __builtin_amdgcn_mfma_f32_16x16x32_bf16(af[fm][k], bfr[j][k], acc[fm][j], 0, 0, 0);
    __builtin_amdgcn_s_setprio(0);

    // ---- P1: A x H1 ----
    #pragma unroll
    for (int j = 0; j < 2; j++)
      #pragma unroll
      for (int k = 0; k < 2; k++) bfr[j][k] = RDB(cur, 1, j, k);
    STAGE_B(2, ks, nxt);
    __builtin_amdgcn_s_setprio(1);
    #pragma unroll
    for (int fm = 0; fm < 4; fm++)
      #pragma unroll
      for (int j = 0; j < 2; j++)
        #pragma unroll
        for (int k = 0; k < 2; k++)
          acc[fm][2 + j] = __builtin_amdgcn_mfma_f32_16x16x32_bf16(af[fm][k], bfr[j][k], acc[fm][2 + j], 0, 0, 0);
    __builtin_amdgcn_s_setprio(0);

    // ---- P2: A x H2 ----
    #pragma unroll
    for (int j = 0; j < 2; j++)
      #pragma unroll
      for (int k = 0; k < 2; k++) bfr[j][k] = RDB(cur, 2, j, k);
    __builtin_amdgcn_s_setprio(1);
    #pragma unroll
    for (int fm = 0; fm < 4; fm++)
      #pragma unroll
      for (int j = 0; j < 2; j++)
        #pragma unroll
        for (int k = 0; k < 2; k++)
          acc[fm][4 + j] = __builtin_amdgcn_mfma_f32_16x16x32_bf16(af[fm][k], bfr[j][k], acc[fm][4 + j], 0, 0, 0);
    __builtin_amdgcn_s_setprio(0);
    BARRIER();   // B_end: all cur reads done before kt+1 writes into it
  }

  #pragma unroll
  for (int fm = 0; fm < 4; fm++)
    #pragma unroll
    for (int fj = 0; fj < 6; fj++) {
      const long row0 = m0 + wm * 64 + fm * 16 + g * 4;
      const long col  = n0 + fj * 64 + wn * 16 + l16;
      if (col < 2048) {
        #pragma unroll
        for (int i = 0; i < 4; i++) Qo[(row0 + i) * 2048 + col] = f2bf(acc[fm][fj][i] * QSC);
      } else if (col < 4096) {
        #pragma unroll
        for (int i = 0; i < 4; i++) Ko[(row0 + i) * 2048 + (col - 2048)] = f2bf(acc[fm][fj][i]);
      } else {
        const long c2 = col - 4096;
        const long base = (((row0 >> 11) * 16 + (c2 >> 7)) * 128 + (c2 & 127)) * 2048 + (row0 & 2047);
        short4v pk;
        #pragma unroll
        for (int i = 0; i < 4; i++) pk[i] = f2bf(acc[fm][fj][i]);
        *reinterpret_cast<short4v*>(Vt + base) = pk;
      }
    }
  #undef STAGE_A
  #undef STAGE_B
  #undef RDA
  #undef RDB
}

// ---------------- out-proj GEMM: 128x256 tile, BK=64, 1-vmcnt/2-barrier per kt ----------------
// Same proof as gemm_qkv8: at kt's WAITVM(4): outstanding = kt-1's {H1'}(2) + {A'',H0''}(4);
// keep 4 newest => retires all of cur (A',H0',H1'). Prologue 6 GLD retired at kt=0 (10 out, keep 4).
__global__ __launch_bounds__(512, 2) void gemm_o2(const short* __restrict__ A,
                                                  const short* __restrict__ W,
                                                  float* __restrict__ C) {
  __shared__ __align__(1024) char lds[98304];   // 2 buf x (A 16KB + B 32KB)
  const int tid  = threadIdx.x;
  const int lane = tid & 63;
  const int w    = tid >> 6;
  const int wm   = w >> 2, wn = w & 3;
  const int l16  = lane & 15, g = lane >> 4;
  const int K    = 2048;

  int id = (int)blockIdx.x;
  id = (id & 7) * 32 + (id >> 3);
  const int mb = id & 31, nb = id >> 5;
  const long m0 = (long)mb * 128, n0 = (long)nb * 256;

  const int srow = lane >> 3;
  const int scol = ((lane & 7) ^ srow) * 8;
  const int csw  = (l16 & 7) << 4;

  f32x4 acc[4][4];
  #pragma unroll
  for (int a = 0; a < 4; a++)
    #pragma unroll
    for (int b = 0; b < 4; b++) acc[a][b] = (f32x4){0.f, 0.f, 0.f, 0.f};

  #define OSTAGE_A(kt, buf)                                                         \
    {                                                                               \
      const short* s0_ = A + (m0 + w * 16 + srow) * K + (kt) * 64 + scol;           \
      char* d_ = lds + (buf) * 49152 + (w * 16) * 128;                              \
      GLD16(s0_, d_);                                                               \
      GLD16(s0_ + 8LL * K, d_ + 1024);                                              \
    }
  #define OSTAGE_B(h, kt, buf)                                                      \
    {                                                                               \
      const short* s0_ = W + (n0 + (h) * 128 + w * 16 + srow) * K + (kt) * 64 + scol; \
      char* d_ = lds + (buf) * 49152 + 16384 + (h) * 16384 + (w * 16) * 128;        \
      GLD16(s0_, d_);                                                               \
      GLD16(s0_ + 8LL * K, d_ + 1024);                                              \
    }
  #define ORDA(buf, fmL, k) (*reinterpret_cast<const bf16x8*>(                      \
      lds + (buf) * 49152 + ((wm * 64 + (fmL) * 16 + l16) * 128) +                  \
      ((((k) * 64 + g * 16)) ^ csw)))
  #define ORDB(buf, h, j, k) (*reinterpret_cast<const bf16x8*>(                     \
      lds + (buf) * 49152 + 16384 + (h) * 16384 +                                   \
      ((wn * 16 + (j) * 64 + l16) * 128) + ((((k) * 64 + g * 16)) ^ csw)))

  OSTAGE_A(0, 0);
  OSTAGE_B(0, 0, 0);
  OSTAGE_B(1, 0, 0);

  bf16x8 af[4][2], bfr[2][2];
  for (int kt = 0; kt < 32; ++kt) {
    const int cur = kt & 1, nxt = cur ^ 1;
    const int ks = (kt + 1 < 32) ? (kt + 1) : kt;

    OSTAGE_A(ks, nxt);
    OSTAGE_B(0, ks, nxt);
    WAITVM(4);
    BARRIER();   // B_pub

    // ---- P0 ----
    #pragma unroll
    for (int fm = 0; fm < 4; fm++)
      #pragma unroll
      for (int k = 0; k < 2; k++) af[fm][k] = ORDA(cur, fm, k);
    #pragma unroll
    for (int j = 0; j < 2; j++)
      #pragma unroll
      for (int k = 0; k < 2; k++) bfr[j][k] = ORDB(cur, 0, j, k);
    OSTAGE_B(1, ks, nxt);
    __builtin_amdgcn_s_setprio(1);
    #pragma unroll
    for (int fm = 0; fm < 4; fm++)
      #pragma unroll
      for (int j = 0; j < 2; j++)
        #pragma unroll
        for (int k = 0; k < 2; k++)
          acc[fm][j] = __builtin_amdgcn_mfma_f32_16x16x32_bf16(af[fm][k], bfr[j][k], acc[fm][j], 0, 0, 0);
    __builtin_amdgcn_s_setprio(0);

    // ---- P1 ----
    #pragma unroll
    for (int j = 0; j < 2; j++)
      #pragma unroll
      for (int k = 0; k < 2; k++) bfr[j][k] = ORDB(cur, 1, j, k);
    __builtin_amdgcn_s_setprio(1);
    #pragma unroll
    for (int fm = 0; fm < 4; fm++)
      #pragma unroll
      for (int j = 0; j < 2; j++)
        #pragma unroll
        for (int k = 0; k < 2; k++)
          acc[fm][2 + j] = __builtin_amdgcn_mfma_f32_16x16x32_bf16(af[fm][k], bfr[j][k], acc[fm][2 + j], 0, 0, 0);
    __builtin_amdgcn_s_setprio(0);
    BARRIER();   // B_end
  }

  #pragma unroll
  for (int fm = 0; fm < 4; fm++)
    #pragma unroll
    for (int fn = 0; fn < 4; fn++) {
      const long row0 = m0 + wm * 64 + fm * 16 + g * 4;
      const long col  = n0 + (fn >> 1) * 128 + (fn & 1) * 64 + wn * 16 + l16;
      #pragma unroll
      for (int i = 0; i < 4; i++) C[(row0 + i) * 2048 + col] = acc[fm][fn][i];
    }
  #undef OSTAGE_A
  #undef OSTAGE_B
  #undef ORDA
  #undef ORDB
}

// ---------------- flash attention v7b (round-12/15 proven, unchanged) ----------------
__global__ __launch_bounds__(256, 3) void attn_kernel(const short* __restrict__ Q,
                                                      const short* __restrict__ K,
                                                      const short* __restrict__ Vt,
                                                      short* __restrict__ Z) {
  __shared__ short Ks[64][128];        // 16KB
  __shared__ short Vs[128][64];        // 16KB
  __shared__ short plds[4][16][64];    // 8KB

  const int tid  = threadIdx.x;
  const int lane = tid & 63;
  const int w    = tid >> 6;
  const int l16  = lane & 15, g = lane >> 4;

  const int bh = blockIdx.x;
  const int bx = 31 - (int)blockIdx.y;    // heavy blocks dispatch first (LPT)
  const int b  = bh >> 4, h = bh & 15;
  const int q0 = bx * 64;

  const float slope2 = exp2f(-0.5f * (float)(h + 1)) * 1.4426950408889634f;
  const float CLAMP2 = 1477.3197f;   // 1024*log2e

  bf16x8 qf[4];
  {
    const long qoff = ((long)(b * 2048 + q0 + w * 16 + l16)) * 2048 + h * 128;
    #pragma unroll
    for (int c = 0; c < 4; c++)
      qf[c] = *reinterpret_cast<const bf16x8*>(Q + qoff + c * 32 + g * 8);
  }

  const f32x4 zero4 = {0.f, 0.f, 0.f, 0.f};
  f32x4 zacc[8];
  #pragma unroll
  for (int s = 0; s < 8; s++) zacc[s] = zero4;
  float m2[4], li[4];
  #pragma unroll
  for (int i = 0; i < 4; i++) { m2[i] = -3e38f; li[i] = 0.f; }

  float aj[4];
  #pragma unroll
  for (int ni = 0; ni < 4; ni++) aj[ni] = slope2 * (float)(ni * 16 + l16);

  const int krow = tid >> 4, kcol = (tid & 15) * 8;   // K: 16 rows x 256B
  const int vrow = tid >> 3, vcol = (tid & 7) * 8;    // V: 32 rows x 128B
  const int kswz = (krow & 7) << 5;
  const int vswz = (vrow & 7) << 4;
  const int rswz = (l16 & 7) << 4;                    // read swz for 128B rows
  const int kr5  = (l16 & 7) << 5;                    // read swz for Ks 256B rows
  const short* Kh = K + ((long)b * 2048) * 2048 + h * 128;
  const short* Vh = Vt + ((long)(b * 16 + h) * 128) * 2048;

  bf16x8 kreg[4], vreg[4];
  #pragma unroll
  for (int j = 0; j < 4; j++)
    kreg[j] = *reinterpret_cast<const bf16x8*>(Kh + (long)(j * 16 + krow) * 2048 + kcol);
  #pragma unroll
  for (int j = 0; j < 4; j++)
    vreg[j] = *reinterpret_cast<const bf16x8*>(Vh + (long)(j * 32 + vrow) * 2048 + vcol);

  const int ntiles = bx + 1;
  for (int t = 0; t < ntiles; t++) {
    const int kv0 = t * 64;
    __syncthreads();
    #pragma unroll
    for (int j = 0; j < 4; j++)
      *reinterpret_cast<bf16x8*>(reinterpret_cast<char*>(Ks) +
          (j * 16 + krow) * 256 + ((kcol * 2) ^ kswz)) = kreg[j];
    #pragma unroll
    for (int j = 0; j < 4; j++)
      *reinterpret_cast<bf16x8*>(reinterpret_cast<char*>(Vs) +
          (j * 32 + vrow) * 128 + ((vcol * 2) ^ vswz)) = vreg[j];
    __syncthreads();

    f32x4 sc[4];
    #pragma unroll
    for (int ni = 0; ni < 4; ni++) sc[ni] = zero4;
    #pragma unroll
    for (int ni = 0; ni < 4; ni++)
      #pragma unroll
      for (int kc = 0; kc < 4; kc++) {
        const bf16x8 kf = *reinterpret_cast<const bf16x8*>(
            reinterpret_cast<const char*>(Ks) + (ni * 16 + l16) * 256 + ((kc * 64 + g * 16) ^ kr5));
        sc[ni] = __builtin_amdgcn_mfma_f32_16x16x32_bf16(qf[kc], kf, sc[ni], 0, 0, 0);
      }

    if (t + 1 < ntiles) {
      const short* kb = Kh + (long)(kv0 + 64) * 2048;
      const short* vb = Vh + kv0 + 64;
      #pragma unroll
      for (int j = 0; j < 4; j++)
        kreg[j] = *reinterpret_cast<const bf16x8*>(kb + (long)(j * 16 + krow) * 2048 + kcol);
      #pragma unroll
      for (int j = 0; j < 4; j++)
        vreg[j] = *reinterpret_cast<const bf16x8*>(vb + (long)(j * 32 + vrow) * 2048 + vcol);
    }

    // clamp / +alibi / mask; per-lane row max (fast path: no cross-lane)
    const float bk = slope2 * (float)kv0;
    float bn[4];
    #pragma unroll
    for (int ni = 0; ni < 4; ni++) bn[ni] = bk + aj[ni];
    float rmax[4];
    float slack = -3e38f;
    #pragma unroll
    for (int i = 0; i < 4; i++) {
      const int qi = q0 + w * 16 + g * 4 + i;
      float mx = -3e38f;
      #pragma unroll
      for (int ni = 0; ni < 4; ni++) {
        const int j = kv0 + ni * 16 + l16;
        float v = fminf(fmaxf(sc[ni][i], -CLAMP2), CLAMP2) + bn[ni];
        v = (j <= qi) ? v : -3e38f;
        sc[ni][i] = v;
        mx = fmaxf(mx, v);
      }
      rmax[i] = mx;
      slack = fmaxf(slack, mx - m2[i]);
    }
    if (__any(slack > 10.f)) {
      #pragma unroll
      for (int i = 0; i < 4; i++) {
        float bb = rmax[i];
        #pragma unroll
        for (int ms = 1; ms < 16; ms <<= 1) bb = fmaxf(bb, __shfl_xor(bb, ms));
        const float mnew = fmaxf(m2[i], bb);
        const float corr = fexp2(m2[i] - mnew);
        m2[i] = mnew;
        li[i] *= corr;
        #pragma unroll
        for (int s = 0; s < 8; s++) zacc[s][i] *= corr;
      }
    }
    // exp2, lane-partial li, P -> plds (swizzled scalar writes)
    char* pbase = reinterpret_cast<char*>(plds) + w * 2048;
    #pragma unroll
    for (int i = 0; i < 4; i++) {
      const int prow = g * 4 + i;
      const int pswz = (prow & 7) << 4;
      float psum = 0.f;
      #pragma unroll
      for (int ni = 0; ni < 4; ni++) {
        const float p = fexp2(sc[ni][i] - m2[i]);
        *reinterpret_cast<short*>(pbase + prow * 128 + (((ni * 16 + l16) * 2) ^ pswz)) = f2bf(p);
        psum += p;
      }
      li[i] += psum;
    }

    bf16x8 paf[2];
    #pragma unroll
    for (int kk = 0; kk < 2; kk++)
      paf[kk] = *reinterpret_cast<const bf16x8*>(
          pbase + l16 * 128 + ((kk * 64 + g * 16) ^ rswz));
    #pragma unroll
    for (int s = 0; s < 8; s++) {
      const char* vr = reinterpret_cast<const char*>(Vs) + (s * 16 + l16) * 128;
      const bf16x8 vf0 = *reinterpret_cast<const bf16x8*>(vr + ((g * 16) ^ rswz));
      const bf16x8 vf1 = *reinterpret_cast<const bf16x8*>(vr + ((64 + g * 16) ^ rswz));
      zacc[s] = __builtin_amdgcn_mfma_f32_16x16x32_bf16(paf[0], vf0, zacc[s], 0, 0, 0);
      zacc[s] = __builtin_amdgcn_mfma_f32_16x16x32_bf16(paf[1], vf1, zacc[s], 0, 0, 0);
    }
  }

  #pragma unroll
  for (int i = 0; i < 4; i++) {
    float s = li[i];
    #pragma unroll
    for (int ms = 1; ms < 16; ms <<= 1) s += __shfl_xor(s, ms);
    li[i] = s;
  }
  #pragma unroll
  for (int s = 0; s < 8; s++)
    #pragma unroll
    for (int i = 0; i < 4; i++) {
      const int qi = q0 + w * 16 + g * 4 + i;
      const float zv = zacc[s][i] / li[i];
      Z[((long)(b * 2048 + qi)) * 2048 + h * 128 + s * 16 + l16] = f2bf(zv);
    }
}

// ---------------- launch ----------------
extern "C" void kernel_launch(void* const* d_in, const int* in_sizes, int n_in,
                              void* d_out, int out_size, void* d_ws, size_t ws_size,
                              hipStream_t stream) {
  const float* X  = (const float*)d_in[0];
  const float* Wq = (const float*)d_in[1];
  const float* Wk = (const float*)d_in[2];
  const float* Wv = (const float*)d_in[3];
  const float* Wo = (const float*)d_in[4];
  float* out = (float*)d_out;

  short* ws    = (short*)d_ws;
  short* Xb    = ws;                     // 8,388,608
  short* Wqkvb = ws + 8388608;           // 12,582,912 (Wq|Wk|Wv rows)
  short* Wob   = ws + 20971520;          // 4,194,304
  short* Qb    = ws + 25165824;          // 8,388,608
  short* Kb    = ws + 33554432;          // 8,388,608
  short* Vtb   = ws + 41943040;          // 8,388,608
  short* Zb    = Xb;

  dim3 gc(2048, 6);
  cast6_kernel<<<gc, 256, 0, stream>>>(X, Wq, Wk, Wv, Wo, Xb, Wqkvb, Wob);

  gemm_qkv8<<<512, 512, 0, stream>>>(Xb, Wqkvb, Qb, Kb, Vtb);

  dim3 ga(32, 32);   // x = head (bh), y = q-slot; bx = 31 - y (heavy first)
  attn_kernel<<<ga, 256, 0, stream>>>(Qb, Kb, Vtb, Zb);

  gemm_o2<<<256, 512, 0, stream>>>(Zb, Wob, out);
}

// Round 18
// 234.067 us; speedup vs baseline: 1.0037x; 1.0037x over previous
//
#include <hip/hip_runtime.h>
#include <hip/hip_bf16.h>

typedef __attribute__((ext_vector_type(4))) float f32x4;
typedef __attribute__((ext_vector_type(8))) short bf16x8;
typedef __attribute__((ext_vector_type(4))) short short4v;

__device__ __forceinline__ short f2bf(float f) {
  union { float f; unsigned u; } x; x.f = f;
  unsigned r = x.u + 0x7fffu + ((x.u >> 16) & 1u);
  return (short)(r >> 16);
}

__device__ __forceinline__ float fexp2(float x) {
#if __has_builtin(__builtin_amdgcn_exp2f)
  return __builtin_amdgcn_exp2f(x);
#else
  return exp2f(x);
#endif
}

#define WAITVM(n) { asm volatile("s_waitcnt vmcnt(" #n ")" ::: "memory"); __builtin_amdgcn_sched_barrier(0); }
#define BARRIER() { __builtin_amdgcn_sched_barrier(0); asm volatile("s_barrier" ::: "memory"); __builtin_amdgcn_sched_barrier(0); }
#define GLD16(g, l) __builtin_amdgcn_global_load_lds((const __attribute__((address_space(1))) void*)(g), (__attribute__((address_space(3))) void*)(l), 16, 0, 0)

// Q pre-scale folded into the QKV GEMM epilogue: 1/sqrt(dh) * log2(e)
#define QSC (0.08838834764831845f * 1.4426950408889634f)

// ---------------- fused cast f32 -> bf16 (RNE), 8 elems/thread, 6 slices ----------------
__global__ __launch_bounds__(256) void cast6_kernel(const float* __restrict__ x,
                                                    const float* __restrict__ w0,
                                                    const float* __restrict__ w1,
                                                    const float* __restrict__ w2,
                                                    const float* __restrict__ w3,
                                                    short* __restrict__ xb,
                                                    short* __restrict__ qkv,
                                                    short* __restrict__ wo) {
  const int y = blockIdx.y;
  const float* in;
  short* out;
  if (y < 3)      { in = (y == 0) ? w0 : (y == 1) ? w1 : w2; out = qkv + (long)y * 4194304; }
  else if (y == 3){ in = w3; out = wo; }
  else            { in = x + (long)(y - 4) * 4194304; out = xb + (long)(y - 4) * 4194304; }
  const int i = blockIdx.x * 256 + threadIdx.x;
  const float4 a = reinterpret_cast<const float4*>(in)[2 * i];
  const float4 b = reinterpret_cast<const float4*>(in)[2 * i + 1];
  bf16x8 s;
  s[0] = f2bf(a.x); s[1] = f2bf(a.y); s[2] = f2bf(a.z); s[3] = f2bf(a.w);
  s[4] = f2bf(b.x); s[5] = f2bf(b.y); s[6] = f2bf(b.z); s[7] = f2bf(b.w);
  reinterpret_cast<bf16x8*>(out)[i] = s;
}

// ---------------- fused QKV GEMM: 128x384 tile, BK=64, 3-phase counted-vmcnt ----------------
// Round-16 proven structure (best measured). Race proof (round 8): P0 vmcnt(6) retires
// H1^kt, P1 vmcnt(6) retires H2^kt, P2 vmcnt(4) retires {A,H0}^(kt+1) — each half
// published >= 1 phase before first read at that phase's PRE-MFMA barrier. Post-MFMA
// barriers at P0/P1 removed (proven redundant); P2's retained = kt-boundary WAR fence.
__global__ __launch_bounds__(512, 2) void gemm_qkv8(const short* __restrict__ A,
                                                    const short* __restrict__ W,
                                                    short* __restrict__ Qo,
                                                    short* __restrict__ Ko,
                                                    short* __restrict__ Vt) {
  __shared__ __align__(1024) char lds[131072];   // 2 buf x 64KB
  const int tid  = threadIdx.x;
  const int lane = tid & 63;
  const int w    = tid >> 6;
  const int wm   = w >> 2, wn = w & 3;
  const int l16  = lane & 15, g = lane >> 4;
  const int K    = 2048;

  int id = (int)blockIdx.x;
  id = (id & 7) * 64 + (id >> 3);
  const int mb = id & 31, nb = id >> 5;
  const long m0 = (long)mb * 128, n0 = (long)nb * 384;

  const int srow = lane >> 3;
  const int scol = ((lane & 7) ^ srow) * 8;
  const int csw  = (l16 & 7) << 4;

  f32x4 acc[4][6];
  #pragma unroll
  for (int a = 0; a < 4; a++)
    #pragma unroll
    for (int b = 0; b < 6; b++) acc[a][b] = (f32x4){0.f, 0.f, 0.f, 0.f};

  #define STAGE_A(kt, buf)                                                          \
    {                                                                               \
      const short* s0_ = A + (m0 + w * 16 + srow) * K + (kt) * 64 + scol;           \
      char* d_ = lds + (buf) * 65536 + (w * 16) * 128;                              \
      GLD16(s0_, d_);                                                               \
      GLD16(s0_ + 8LL * K, d_ + 1024);                                              \
    }
  #define STAGE_B(h, kt, buf)                                                       \
    {                                                                               \
      const short* s0_ = W + (n0 + (h) * 128 + w * 16 + srow) * K + (kt) * 64 + scol; \
      char* d_ = lds + (buf) * 65536 + 16384 + (h) * 16384 + (w * 16) * 128;        \
      GLD16(s0_, d_);                                                               \
      GLD16(s0_ + 8LL * K, d_ + 1024);                                              \
    }

  #define RDA(buf, fmL, k) (*reinterpret_cast<const bf16x8*>(                       \
      lds + (buf) * 65536 + ((wm * 64 + (fmL) * 16 + l16) * 128) +                  \
      ((((k) * 64 + g * 16)) ^ csw)))
  #define RDB(buf, h, j, k) (*reinterpret_cast<const bf16x8*>(                      \
      lds + (buf) * 65536 + 16384 + (h) * 16384 +                                   \
      ((wn * 16 + (j) * 64 + l16) * 128) + ((((k) * 64 + g * 16)) ^ csw)))

  STAGE_A(0, 0);
  STAGE_B(0, 0, 0);
  STAGE_B(1, 0, 0);
  STAGE_B(2, 0, 0);
  WAITVM(4);
  BARRIER();

  bf16x8 af[4][2], bfr[2][2];
  for (int kt = 0; kt < 32; ++kt) {
    const int cur = kt & 1, nxt = cur ^ 1;
    const int ks = (kt + 1 < 32) ? (kt + 1) : kt;

    // ---- P0 ----
    #pragma unroll
    for (int fm = 0; fm < 4; fm++)
      #pragma unroll
      for (int k = 0; k < 2; k++) af[fm][k] = RDA(cur, fm, k);
    #pragma unroll
    for (int j = 0; j < 2; j++)
      #pragma unroll
      for (int k = 0; k < 2; k++) bfr[j][k] = RDB(cur, 0, j, k);
    STAGE_A(ks, nxt);
    STAGE_B(0, ks, nxt);
    WAITVM(6);
    BARRIER();
    __builtin_amdgcn_s_setprio(1);
    #pragma unroll
    for (int fm = 0; fm < 4; fm++)
      #pragma unroll
      for (int j = 0; j < 2; j++)
        #pragma unroll
        for (int k = 0; k < 2; k++)
          acc[fm][j] = __builtin_amdgcn_mfma_f32_16x16x32_bf16(af[fm][k], bfr[j][k], acc[fm][j], 0, 0, 0);
    __builtin_amdgcn_s_setprio(0);

    // ---- P1 ----
    #pragma unroll
    for (int j = 0; j < 2; j++)
      #pragma unroll
      for (int k = 0; k < 2; k++) bfr[j][k] = RDB(cur, 1, j, k);
    STAGE_B(1, ks, nxt);
    WAITVM(6);
    BARRIER();
    __builtin_amdgcn_s_setprio(1);
    #pragma unroll
    for (int fm = 0; fm < 4; fm++)
      #pragma unroll
      for (int j = 0; j < 2; j++)
        #pragma unroll
        for (int k = 0; k < 2; k++)
          acc[fm][2 + j] = __builtin_amdgcn_mfma_f32_16x16x32_bf16(af[fm][k], bfr[j][k], acc[fm][2 + j], 0, 0, 0);
    __builtin_amdgcn_s_setprio(0);

    // ---- P2 ----
    #pragma unroll
    for (int j = 0; j < 2; j++)
      #pragma unroll
      for (int k = 0; k < 2; k++) bfr[j][k] = RDB(cur, 2, j, k);
    STAGE_B(2, ks, nxt);
    WAITVM(4);
    BARRIER();
    __builtin_amdgcn_s_setprio(1);
    #pragma unroll
    for (int fm = 0; fm < 4; fm++)
      #pragma unroll
      for (int j = 0; j < 2; j++)
        #pragma unroll
        for (int k = 0; k < 2; k++)
          acc[fm][4 + j] = __builtin_amdgcn_mfma_f32_16x16x32_bf16(af[fm][k], bfr[j][k], acc[fm][4 + j], 0, 0, 0);
    __builtin_amdgcn_s_setprio(0);
    BARRIER();   // kt-boundary WAR fence: all cur reads done before kt+1 stages issue
  }

  #pragma unroll
  for (int fm = 0; fm < 4; fm++)
    #pragma unroll
    for (int fj = 0; fj < 6; fj++) {
      const long row0 = m0 + wm * 64 + fm * 16 + g * 4;
      const long col  = n0 + fj * 64 + wn * 16 + l16;
      if (col < 2048) {
        #pragma unroll
        for (int i = 0; i < 4; i++) Qo[(row0 + i) * 2048 + col] = f2bf(acc[fm][fj][i] * QSC);
      } else if (col < 4096) {
        #pragma unroll
        for (int i = 0; i < 4; i++) Ko[(row0 + i) * 2048 + (col - 2048)] = f2bf(acc[fm][fj][i]);
      } else {
        const long c2 = col - 4096;
        const long base = (((row0 >> 11) * 16 + (c2 >> 7)) * 128 + (c2 & 127)) * 2048 + (row0 & 2047);
        short4v pk;
        #pragma unroll
        for (int i = 0; i < 4; i++) pk[i] = f2bf(acc[fm][fj][i]);
        *reinterpret_cast<short4v*>(Vt + base) = pk;
      }
    }
  #undef STAGE_A
  #undef STAGE_B
  #undef RDA
  #undef RDB
}

// ---------------- out-proj GEMM: 128x256 tile, BK=64, 2-phase counted-vmcnt ----------------
// Round-16 proven structure (race proof round 10; P0 post-MFMA barrier removed,
// P1's retained as kt-boundary WAR fence).
__global__ __launch_bounds__(512, 2) void gemm_o2(const short* __restrict__ A,
                                                  const short* __restrict__ W,
                                                  float* __restrict__ C) {
  __shared__ __align__(1024) char lds[98304];   // 2 buf x (A 16KB + B 32KB)
  const int tid  = threadIdx.x;
  const int lane = tid & 63;
  const int w    = tid >> 6;
  const int wm   = w >> 2, wn = w & 3;
  const int l16  = lane & 15, g = lane >> 4;
  const int K    = 2048;

  int id = (int)blockIdx.x;
  id = (id & 7) * 32 + (id >> 3);
  const int mb = id & 31, nb = id >> 5;
  const long m0 = (long)mb * 128, n0 = (long)nb * 256;

  const int srow = lane >> 3;
  const int scol = ((lane & 7) ^ srow) * 8;
  const int csw  = (l16 & 7) << 4;

  f32x4 acc[4][4];
  #pragma unroll
  for (int a = 0; a < 4; a++)
    #pragma unroll
    for (int b = 0; b < 4; b++) acc[a][b] = (f32x4){0.f, 0.f, 0.f, 0.f};

  #define OSTAGE_A(kt, buf)                                                         \
    {                                                                               \
      const short* s0_ = A + (m0 + w * 16 + srow) * K + (kt) * 64 + scol;           \
      char* d_ = lds + (buf) * 49152 + (w * 16) * 128;                              \
      GLD16(s0_, d_);                                                               \
      GLD16(s0_ + 8LL * K, d_ + 1024);                                              \
    }
  #define OSTAGE_B(h, kt, buf)                                                      \
    {                                                                               \
      const short* s0_ = W + (n0 + (h) * 128 + w * 16 + srow) * K + (kt) * 64 + scol; \
      char* d_ = lds + (buf) * 49152 + 16384 + (h) * 16384 + (w * 16) * 128;        \
      GLD16(s0_, d_);                                                               \
      GLD16(s0_ + 8LL * K, d_ + 1024);                                              \
    }
  #define ORDA(buf, fmL, k) (*reinterpret_cast<const bf16x8*>(                      \
      lds + (buf) * 49152 + ((wm * 64 + (fmL) * 16 + l16) * 128) +                  \
      ((((k) * 64 + g * 16)) ^ csw)))
  #define ORDB(buf, h, j, k) (*reinterpret_cast<const bf16x8*>(                     \
      lds + (buf) * 49152 + 16384 + (h) * 16384 +                                   \
      ((wn * 16 + (j) * 64 + l16) * 128) + ((((k) * 64 + g * 16)) ^ csw)))

  OSTAGE_A(0, 0);
  OSTAGE_B(0, 0, 0);
  OSTAGE_B(1, 0, 0);
  WAITVM(2);
  BARRIER();

  bf16x8 af[4][2], bfr[2][2];
  for (int kt = 0; kt < 32; ++kt) {
    const int cur = kt & 1, nxt = cur ^ 1;
    const int ks = (kt + 1 < 32) ? (kt + 1) : kt;

    // ---- P0 ----
    #pragma unroll
    for (int fm = 0; fm < 4; fm++)
      #pragma unroll
      for (int k = 0; k < 2; k++) af[fm][k] = ORDA(cur, fm, k);
    #pragma unroll
    for (int j = 0; j < 2; j++)
      #pragma unroll
      for (int k = 0; k < 2; k++) bfr[j][k] = ORDB(cur, 0, j, k);
    OSTAGE_A(ks, nxt);
    OSTAGE_B(0, ks, nxt);
    WAITVM(4);
    BARRIER();
    __builtin_amdgcn_s_setprio(1);
    #pragma unroll
    for (int fm = 0; fm < 4; fm++)
      #pragma unroll
      for (int j = 0; j < 2; j++)
        #pragma unroll
        for (int k = 0; k < 2; k++)
          acc[fm][j] = __builtin_amdgcn_mfma_f32_16x16x32_bf16(af[fm][k], bfr[j][k], acc[fm][j], 0, 0, 0);
    __builtin_amdgcn_s_setprio(0);

    // ---- P1 ----
    #pragma unroll
    for (int j = 0; j < 2; j++)
      #pragma unroll
      for (int k = 0; k < 2; k++) bfr[j][k] = ORDB(cur, 1, j, k);
    OSTAGE_B(1, ks, nxt);
    WAITVM(2);
    BARRIER();
    __builtin_amdgcn_s_setprio(1);
    #pragma unroll
    for (int fm = 0; fm < 4; fm++)
      #pragma unroll
      for (int j = 0; j < 2; j++)
        #pragma unroll
        for (int k = 0; k < 2; k++)
          acc[fm][2 + j] = __builtin_amdgcn_mfma_f32_16x16x32_bf16(af[fm][k], bfr[j][k], acc[fm][2 + j], 0, 0, 0);
    __builtin_amdgcn_s_setprio(0);
    BARRIER();   // kt-boundary WAR fence
  }

  #pragma unroll
  for (int fm = 0; fm < 4; fm++)
    #pragma unroll
    for (int fn = 0; fn < 4; fn++) {
      const long row0 = m0 + wm * 64 + fm * 16 + g * 4;
      const long col  = n0 + (fn >> 1) * 128 + (fn & 1) * 64 + wn * 16 + l16;
      #pragma unroll
      for (int i = 0; i < 4; i++) C[(row0 + i) * 2048 + col] = acc[fm][fn][i];
    }
  #undef OSTAGE_A
  #undef OSTAGE_B
  #undef ORDA
  #undef ORDB
}

// ---------------- flash attention v7b (round-12/15 proven, unchanged) ----------------
__global__ __launch_bounds__(256, 3) void attn_kernel(const short* __restrict__ Q,
                                                      const short* __restrict__ K,
                                                      const short* __restrict__ Vt,
                                                      short* __restrict__ Z) {
  __shared__ short Ks[64][128];        // 16KB
  __shared__ short Vs[128][64];        // 16KB
  __shared__ short plds[4][16][64];    // 8KB

  const int tid  = threadIdx.x;
  const int lane = tid & 63;
  const int w    = tid >> 6;
  const int l16  = lane & 15, g = lane >> 4;

  const int bh = blockIdx.x;
  const int bx = 31 - (int)blockIdx.y;    // heavy blocks dispatch first (LPT)
  const int b  = bh >> 4, h = bh & 15;
  const int q0 = bx * 64;

  const float slope2 = exp2f(-0.5f * (float)(h + 1)) * 1.4426950408889634f;
  const float CLAMP2 = 1477.3197f;   // 1024*log2e

  bf16x8 qf[4];
  {
    const long qoff = ((long)(b * 2048 + q0 + w * 16 + l16)) * 2048 + h * 128;
    #pragma unroll
    for (int c = 0; c < 4; c++)
      qf[c] = *reinterpret_cast<const bf16x8*>(Q + qoff + c * 32 + g * 8);
  }

  const f32x4 zero4 = {0.f, 0.f, 0.f, 0.f};
  f32x4 zacc[8];
  #pragma unroll
  for (int s = 0; s < 8; s++) zacc[s] = zero4;
  float m2[4], li[4];
  #pragma unroll
  for (int i = 0; i < 4; i++) { m2[i] = -3e38f; li[i] = 0.f; }

  float aj[4];
  #pragma unroll
  for (int ni = 0; ni < 4; ni++) aj[ni] = slope2 * (float)(ni * 16 + l16);

  const int krow = tid >> 4, kcol = (tid & 15) * 8;   // K: 16 rows x 256B
  const int vrow = tid >> 3, vcol = (tid & 7) * 8;    // V: 32 rows x 128B
  const int kswz = (krow & 7) << 5;
  const int vswz = (vrow & 7) << 4;
  const int rswz = (l16 & 7) << 4;                    // read swz for 128B rows
  const int kr5  = (l16 & 7) << 5;                    // read swz for Ks 256B rows
  const short* Kh = K + ((long)b * 2048) * 2048 + h * 128;
  const short* Vh = Vt + ((long)(b * 16 + h) * 128) * 2048;

  bf16x8 kreg[4], vreg[4];
  #pragma unroll
  for (int j = 0; j < 4; j++)
    kreg[j] = *reinterpret_cast<const bf16x8*>(Kh + (long)(j * 16 + krow) * 2048 + kcol);
  #pragma unroll
  for (int j = 0; j < 4; j++)
    vreg[j] = *reinterpret_cast<const bf16x8*>(Vh + (long)(j * 32 + vrow) * 2048 + vcol);

  const int ntiles = bx + 1;
  for (int t = 0; t < ntiles; t++) {
    const int kv0 = t * 64;
    __syncthreads();
    #pragma unroll
    for (int j = 0; j < 4; j++)
      *reinterpret_cast<bf16x8*>(reinterpret_cast<char*>(Ks) +
          (j * 16 + krow) * 256 + ((kcol * 2) ^ kswz)) = kreg[j];
    #pragma unroll
    for (int j = 0; j < 4; j++)
      *reinterpret_cast<bf16x8*>(reinterpret_cast<char*>(Vs) +
          (j * 32 + vrow) * 128 + ((vcol * 2) ^ vswz)) = vreg[j];
    __syncthreads();

    f32x4 sc[4];
    #pragma unroll
    for (int ni = 0; ni < 4; ni++) sc[ni] = zero4;
    #pragma unroll
    for (int ni = 0; ni < 4; ni++)
      #pragma unroll
      for (int kc = 0; kc < 4; kc++) {
        const bf16x8 kf = *reinterpret_cast<const bf16x8*>(
            reinterpret_cast<const char*>(Ks) + (ni * 16 + l16) * 256 + ((kc * 64 + g * 16) ^ kr5));
        sc[ni] = __builtin_amdgcn_mfma_f32_16x16x32_bf16(qf[kc], kf, sc[ni], 0, 0, 0);
      }

    if (t + 1 < ntiles) {
      const short* kb = Kh + (long)(kv0 + 64) * 2048;
      const short* vb = Vh + kv0 + 64;
      #pragma unroll
      for (int j = 0; j < 4; j++)
        kreg[j] = *reinterpret_cast<const bf16x8*>(kb + (long)(j * 16 + krow) * 2048 + kcol);
      #pragma unroll
      for (int j = 0; j < 4; j++)
        vreg[j] = *reinterpret_cast<const bf16x8*>(vb + (long)(j * 32 + vrow) * 2048 + vcol);
    }

    // clamp / +alibi / mask; per-lane row max (fast path: no cross-lane)
    const float bk = slope2 * (float)kv0;
    float bn[4];
    #pragma unroll
    for (int ni = 0; ni < 4; ni++) bn[ni] = bk + aj[ni];
    float rmax[4];
    float slack = -3e38f;
    #pragma unroll
    for (int i = 0; i < 4; i++) {
      const int qi = q0 + w * 16 + g * 4 + i;
      float mx = -3e38f;
      #pragma unroll
      for (int ni = 0; ni < 4; ni++) {
        const int j = kv0 + ni * 16 + l16;
        float v = fminf(fmaxf(sc[ni][i], -CLAMP2), CLAMP2) + bn[ni];
        v = (j <= qi) ? v : -3e38f;
        sc[ni][i] = v;
        mx = fmaxf(mx, v);
      }
      rmax[i] = mx;
      slack = fmaxf(slack, mx - m2[i]);
    }
    if (__any(slack > 10.f)) {
      #pragma unroll
      for (int i = 0; i < 4; i++) {
        float bb = rmax[i];
        #pragma unroll
        for (int ms = 1; ms < 16; ms <<= 1) bb = fmaxf(bb, __shfl_xor(bb, ms));
        const float mnew = fmaxf(m2[i], bb);
        const float corr = fexp2(m2[i] - mnew);
        m2[i] = mnew;
        li[i] *= corr;
        #pragma unroll
        for (int s = 0; s < 8; s++) zacc[s][i] *= corr;
      }
    }
    // exp2, lane-partial li, P -> plds (swizzled scalar writes)
    char* pbase = reinterpret_cast<char*>(plds) + w * 2048;
    #pragma unroll
    for (int i = 0; i < 4; i++) {
      const int prow = g * 4 + i;
      const int pswz = (prow & 7) << 4;
      float psum = 0.f;
      #pragma unroll
      for (int ni = 0; ni < 4; ni++) {
        const float p = fexp2(sc[ni][i] - m2[i]);
        *reinterpret_cast<short*>(pbase + prow * 128 + (((ni * 16 + l16) * 2) ^ pswz)) = f2bf(p);
        psum += p;
      }
      li[i] += psum;
    }

    bf16x8 paf[2];
    #pragma unroll
    for (int kk = 0; kk < 2; kk++)
      paf[kk] = *reinterpret_cast<const bf16x8*>(
          pbase + l16 * 128 + ((kk * 64 + g * 16) ^ rswz));
    #pragma unroll
    for (int s = 0; s < 8; s++) {
      const char* vr = reinterpret_cast<const char*>(Vs) + (s * 16 + l16) * 128;
      const bf16x8 vf0 = *reinterpret_cast<const bf16x8*>(vr + ((g * 16) ^ rswz));
      const bf16x8 vf1 = *reinterpret_cast<const bf16x8*>(vr + ((64 + g * 16) ^ rswz));
      zacc[s] = __builtin_amdgcn_mfma_f32_16x16x32_bf16(paf[0], vf0, zacc[s], 0, 0, 0);
      zacc[s] = __builtin_amdgcn_mfma_f32_16x16x32_bf16(paf[1], vf1, zacc[s], 0, 0, 0);
    }
  }

  #pragma unroll
  for (int i = 0; i < 4; i++) {
    float s = li[i];
    #pragma unroll
    for (int ms = 1; ms < 16; ms <<= 1) s += __shfl_xor(s, ms);
    li[i] = s;
  }
  #pragma unroll
  for (int s = 0; s < 8; s++)
    #pragma unroll
    for (int i = 0; i < 4; i++) {
      const int qi = q0 + w * 16 + g * 4 + i;
      const float zv = zacc[s][i] / li[i];
      Z[((long)(b * 2048 + qi)) * 2048 + h * 128 + s * 16 + l16] = f2bf(zv);
    }
}

// ---------------- launch ----------------
extern "C" void kernel_launch(void* const* d_in, const int* in_sizes, int n_in,
                              void* d_out, int out_size, void* d_ws, size_t ws_size,
                              hipStream_t stream) {
  const float* X  = (const float*)d_in[0];
  const float* Wq = (const float*)d_in[1];
  const float* Wk = (const float*)d_in[2];
  const float* Wv = (const float*)d_in[3];
  const float* Wo = (const float*)d_in[4];
  float* out = (float*)d_out;

  short* ws    = (short*)d_ws;
  short* Xb    = ws;                     // 8,388,608
  short* Wqkvb = ws + 8388608;           // 12,582,912 (Wq|Wk|Wv rows)
  short* Wob   = ws + 20971520;          // 4,194,304
  short* Qb    = ws + 25165824;          // 8,388,608
  short* Kb    = ws + 33554432;          // 8,388,608
  short* Vtb   = ws + 41943040;          // 8,388,608
  short* Zb    = Xb;

  dim3 gc(2048, 6);
  cast6_kernel<<<gc, 256, 0, stream>>>(X, Wq, Wk, Wv, Wo, Xb, Wqkvb, Wob);

  gemm_qkv8<<<512, 512, 0, stream>>>(Xb, Wqkvb, Qb, Kb, Vtb);

  dim3 ga(32, 32);   // x = head (bh), y = q-slot; bx = 31 - y (heavy first)
  attn_kernel<<<ga, 256, 0, stream>>>(Qb, Kb, Vtb, Zb);

  gemm_o2<<<256, 512, 0, stream>>>(Zb, Wob, out);
}